// Round 9
// baseline (284.251 us; speedup 1.0000x reference)
//
#include <hip/hip_runtime.h>
#include <hip/hip_bf16.h>
#include <math.h>

// PaGCN forward, restructured:
//   h0 = relu(AM ⊙ spmm(adjZ, (M⊙x)@W0) + b0)      (spmm gathers 128 bf16 feats)
//   h1 = relu(AM ⊙ spmm(adjZ, (M⊙h0)@W1) + b1)     (spmm gathers 64 bf16 feats)
//   out = log_softmax(spmm(adj, h1@W2) + b2)        (spmm gathers 40 bf16 feats)
//
// R9: XCD-partitioned histogram. R8 showed gemm0_hist writing 42MB vs ~17MB
// legitimate -> ~25MB atomic line ping-pong (cnt shared across 8 XCDs).
// cnt8[8][N] gives each blockIdx&7 partition (HW round-robin -> XCD) a
// private counter array; combine8 + scan + scan_add8 produce absolute
// per-(row,partition) bases; scatter recomputes partition from edge index.
// cnt8 lives in the permanently-unused upper half of the t_f region.
// Carried: no-LDS MFMA gemms (bf16, fp32 accum), bf16 gather targets,
// M folded into spmm128 (M>=0), atomic-free scatter, multi-edge spmm40/64,
// 8-deep spmm128 bursts, NaN-laundering clamps.

typedef __attribute__((ext_vector_type(8))) short bf16x8;
typedef __attribute__((ext_vector_type(4))) float f32x4;

__device__ __forceinline__ float rl_f(float v, int j) {
    return __builtin_bit_cast(float,
        __builtin_amdgcn_readlane(__builtin_bit_cast(int, v), j));
}
__device__ __forceinline__ int rl_i(int v, int j) {
    return __builtin_amdgcn_readlane(v, j);
}
__device__ __forceinline__ unsigned short f2bf(float f) {
    unsigned u = __builtin_bit_cast(unsigned, f);
    u += 0x7fffu + ((u >> 16) & 1u);   // round-to-nearest-even
    return (unsigned short)(u >> 16);
}
__device__ __forceinline__ unsigned pack2bf(float lo, float hi) {
    return (unsigned)f2bf(lo) | ((unsigned)f2bf(hi) << 16);
}
__device__ __forceinline__ float bf_lo(unsigned u) {
    return __builtin_bit_cast(float, u << 16);
}
__device__ __forceinline__ float bf_hi(unsigned u) {
    return __builtin_bit_cast(float, u & 0xffff0000u);
}
__device__ __forceinline__ float clampf(float v) {
    return fminf(fmaxf(v, -1e30f), 1e30f);
}

// ---------------- W prep: Wt[n][k] = bf16(W[k][n]), n zero-padded ----------------

__global__ void prep_wt(const float* __restrict__ W0, const float* __restrict__ W1,
                        const float* __restrict__ W2,
                        unsigned short* __restrict__ wt0, unsigned short* __restrict__ wt1,
                        unsigned short* __restrict__ wt2) {
    int idx = blockIdx.x * 256 + threadIdx.x;
    if (idx < 128 * 128) {                       // wt0: [128][128]
        int nn = idx >> 7, k = idx & 127;
        wt0[idx] = f2bf(W0[k * 128 + nn]);
    }
    idx -= 128 * 128;
    if (idx >= 0 && idx < 64 * 128) {            // wt1: [64][128]
        int nn = idx >> 7, k = idx & 127;
        wt1[idx] = f2bf(W1[k * 64 + nn]);
    }
    idx -= 64 * 128;
    if (idx >= 0 && idx < 48 * 64) {             // wt2: [48][64], n>=40 zero
        int nn = idx >> 6, k = idx & 63;
        wt2[idx] = (nn < 40) ? f2bf(W2[k * 40 + nn]) : (unsigned short)0;
    }
}

// ---------------- MFMA GEMM body (no LDS, no barriers) ----------------
// Block = 4 waves, each wave computes 16 rows x COLS via 16x16x32 bf16 MFMA.
// A: lane supplies row m=lane&15, k=q*8..q*8+7 per 32-chunk; B: col n=lane&15;
// D: row=q*4+reg, col=lane&15.  (HW-verified fragment maps.)

template <int K, int COLS, int NTPAD, bool ABF16, bool MSCALE>
__device__ __forceinline__ void gemm_mfma_body(const void* __restrict__ Asrc,
                                               const float* __restrict__ Mv,
                                               const unsigned short* __restrict__ Wt,
                                               unsigned short* __restrict__ outp,
                                               int n, int bid) {
    constexpr int KS = K / 32;
    const int lane = threadIdx.x & 63;
    const int wid = threadIdx.x >> 6;
    const int m15 = lane & 15;
    const int q = lane >> 4;
    const int rA = bid * 64 + wid * 16 + m15;

    bf16x8 a[KS];
    if constexpr (ABF16) {
        const unsigned short* A = (const unsigned short*)Asrc;
#pragma unroll
        for (int ks = 0; ks < KS; ++ks) {
            uint4 z = make_uint4(0u, 0u, 0u, 0u);
            if (rA < n) z = *(const uint4*)(A + (size_t)rA * K + ks * 32 + q * 8);
            a[ks] = __builtin_bit_cast(bf16x8, z);
        }
    } else {
        const float* A = (const float*)Asrc;
        float m = 1.0f;
        if constexpr (MSCALE) { if (rA < n) m = Mv[rA]; }
#pragma unroll
        for (int ks = 0; ks < KS; ++ks) {
            float4 lo = make_float4(0.f, 0.f, 0.f, 0.f);
            float4 hi = make_float4(0.f, 0.f, 0.f, 0.f);
            if (rA < n) {
                lo = *(const float4*)(A + (size_t)rA * K + ks * 32 + q * 8);
                hi = *(const float4*)(A + (size_t)rA * K + ks * 32 + q * 8 + 4);
            }
            union { bf16x8 v; unsigned short u[8]; } pk;
            pk.u[0] = f2bf(lo.x * m); pk.u[1] = f2bf(lo.y * m);
            pk.u[2] = f2bf(lo.z * m); pk.u[3] = f2bf(lo.w * m);
            pk.u[4] = f2bf(hi.x * m); pk.u[5] = f2bf(hi.y * m);
            pk.u[6] = f2bf(hi.z * m); pk.u[7] = f2bf(hi.w * m);
            a[ks] = pk.v;
        }
    }

#pragma unroll
    for (int nt = 0; nt < NTPAD / 16; ++nt) {
        f32x4 acc = {0.f, 0.f, 0.f, 0.f};
        const int bn = nt * 16 + m15;
#pragma unroll
        for (int ks = 0; ks < KS; ++ks) {
            const uint4 z = *(const uint4*)(Wt + (size_t)bn * K + ks * 32 + q * 8);
            const bf16x8 b = __builtin_bit_cast(bf16x8, z);
            acc = __builtin_amdgcn_mfma_f32_16x16x32_bf16(a[ks], b, acc, 0, 0, 0);
        }
        const int gc = nt * 16 + m15;
#pragma unroll
        for (int rr = 0; rr < 4; ++rr) {
            const int gr = bid * 64 + wid * 16 + q * 4 + rr;
            bool ok = gr < n;
            if constexpr (NTPAD != COLS) ok = ok && (gc < COLS);
            if (ok) outp[(size_t)gr * COLS + gc] = f2bf(clampf(acc[rr]));
        }
    }
}

template <int K, int COLS, int NTPAD, bool ABF16, bool MSCALE>
__launch_bounds__(256)
__global__ void gemm_mfma(const void* __restrict__ A, const float* __restrict__ Mv,
                          const unsigned short* __restrict__ Wt,
                          unsigned short* __restrict__ out, int n) {
    gemm_mfma_body<K, COLS, NTPAD, ABF16, MSCALE>(A, Mv, Wt, out, n, blockIdx.x);
}

// ---------------- fused gemm0 (MFMA) + XCD-partitioned histogram ----------------
// hist partition x = blockIdx & 7 (consecutive blocks round-robin XCDs);
// each partition owns a private cnt8[x][N] slice -> no cross-XCD line ping-pong.

__launch_bounds__(256)
__global__ void gemm0_hist(const float* __restrict__ x, const float* __restrict__ Mv,
                           const unsigned short* __restrict__ Wt0,
                           unsigned short* __restrict__ t_buf,
                           const int* __restrict__ row, int* __restrict__ cnt8,
                           int* __restrict__ pos_local, int n, int E, int gemmBlocks) {
    const int b = blockIdx.x;
    if (b < gemmBlocks) {
        gemm_mfma_body<128, 128, 128, false, true>(x, Mv, Wt0, t_buf, n, b);
    } else {
        const int part = b & 7;
        const int e = (b - gemmBlocks) * 256 + threadIdx.x;
        if (e < E) pos_local[e] = atomicAdd(&cnt8[(size_t)part * n + row[e]], 1);
    }
}

// ---------------- combine: per-row partition bases + row totals ----------------

__global__ void combine8(int* __restrict__ cnt8, int* __restrict__ cnt, int n) {
    const int i = blockIdx.x * 256 + threadIdx.x;
    if (i >= n) return;
    int s = 0;
#pragma unroll
    for (int x = 0; x < 8; ++x) {
        const int t = cnt8[(size_t)x * n + i];
        cnt8[(size_t)x * n + i] = s;     // exclusive prefix within row
        s += t;
    }
    cnt[i] = s;                          // row total
}

// ---------------- scan (exclusive prefix over cnt -> rp) ----------------

__global__ void scan_part(const int* __restrict__ cnt, int* __restrict__ out,
                          int* __restrict__ bsums, int n) {
    __shared__ int sdata[256];
    const int t = threadIdx.x;
    const int base = blockIdx.x * 1024 + t * 4;
    int v[4];
#pragma unroll
    for (int i = 0; i < 4; ++i) v[i] = (base + i < n) ? cnt[base + i] : 0;
    int tsum = v[0] + v[1] + v[2] + v[3];
    sdata[t] = tsum;
    __syncthreads();
    for (int off = 1; off < 256; off <<= 1) {
        int x = (t >= off) ? sdata[t - off] : 0;
        __syncthreads();
        sdata[t] += x;
        __syncthreads();
    }
    int run = sdata[t] - tsum;
    if (t == 255) bsums[blockIdx.x] = sdata[t];
#pragma unroll
    for (int i = 0; i < 4; ++i) {
        if (base + i < n) out[base + i] = run;
        run += v[i];
    }
}

__global__ void scan_top(int* __restrict__ bs, int nb) {
    int t = threadIdx.x;
    int orig = (t < nb) ? bs[t] : 0;
    int v = orig;
#pragma unroll
    for (int off = 1; off < 64; off <<= 1) {
        int x = __shfl_up(v, off);
        if (t >= off) v += x;
    }
    if (t < nb) bs[t] = v - orig;
}

// rp[i] final; cnt8[x][i] += rp[i] -> absolute base per (row, partition)
__global__ void scan_add8(int* __restrict__ rp, const int* __restrict__ bs,
                          int* __restrict__ cnt8, int n, int total) {
    int i = blockIdx.x * blockDim.x + threadIdx.x;
    if (i < n) {
        const int v = rp[i] + bs[i >> 10];
        rp[i] = v;
#pragma unroll
        for (int x = 0; x < 8; ++x) cnt8[(size_t)x * n + i] += v;
    }
    if (i == 0) rp[n] = total;
}

// ---------------- scatter (atomic-free, partition recomputed from e) ----------------

__global__ void scatter_kernel(const int* __restrict__ row, const int* __restrict__ col,
                               const float* __restrict__ vA, const float* __restrict__ vZ,
                               const int* __restrict__ cnt8, const int* __restrict__ pos_local,
                               float* __restrict__ packed, int E, int n, int gemmBlocks) {
    int e = blockIdx.x * blockDim.x + threadIdx.x;
    if (e >= E) return;
    const int part = (gemmBlocks + (e >> 8)) & 7;    // matches hist's blockIdx&7
    const int pos = cnt8[(size_t)part * n + row[e]] + pos_local[e];
    float3 pk;
    pk.x = __int_as_float(col[e]);
    pk.y = vZ[e];
    pk.z = vA[e];
    *(float3*)&packed[(size_t)3 * pos] = pk;
}

// ---------------- SpMM F=128: wave/row, 8-deep bursts; out = M⊙relu(...) bf16 ----------------

__launch_bounds__(256)
__global__ void spmm128_kernel(const float* __restrict__ packed,
                               const int* __restrict__ rp, const unsigned short* __restrict__ X,
                               const float* __restrict__ AM, const float* __restrict__ Mv,
                               const float* __restrict__ bias,
                               unsigned short* __restrict__ out, int n) {
    const int lane = threadIdx.x & 63;
    const int r = (int)((blockIdx.x * (unsigned)blockDim.x + threadIdx.x) >> 6);
    if (r >= n) return;
    const int s = __builtin_amdgcn_readfirstlane(rp[r]);
    const int e = __builtin_amdgcn_readfirstlane(rp[r + 1]);

    float acc0 = 0.0f, acc1 = 0.0f;
    for (int base = s; base < e; base += 64) {
        const int nn = min(64, e - base);
        int ci = 0; float vf = 0.0f;
        if (lane < nn) {
            const float3 pk = *(const float3*)&packed[(size_t)3 * (base + lane)];
            ci = __builtin_bit_cast(int, pk.x);
            vf = pk.y;
        }
        int j = 0;
        for (; j + 8 <= nn; j += 8) {
            unsigned u[8];
#pragma unroll
            for (int q = 0; q < 8; ++q) {
                const int cq = rl_i(ci, j + q);
                u[q] = *(const unsigned*)(X + (size_t)cq * 128 + lane * 2);
            }
#pragma unroll
            for (int q = 0; q < 8; ++q) {
                const float vq = rl_f(vf, j + q);
                acc0 += vq * bf_lo(u[q]);
                acc1 += vq * bf_hi(u[q]);
            }
        }
        for (; j < nn; ++j) {
            const int cq = rl_i(ci, j);
            const float vq = rl_f(vf, j);
            const unsigned u = *(const unsigned*)(X + (size_t)cq * 128 + lane * 2);
            acc0 += vq * bf_lo(u);
            acc1 += vq * bf_hi(u);
        }
    }

    const float am = AM[r];
    const float mr = Mv[r];   // fold M (>=0): M⊙relu(y) = relu(M⊙y)
    const float o0 = fminf(fmaxf((acc0 * am + bias[2 * lane]) * mr, 0.0f), 1e30f);
    const float o1 = fminf(fmaxf((acc1 * am + bias[2 * lane + 1]) * mr, 0.0f), 1e30f);
    ((unsigned*)out)[(size_t)r * 64 + lane] = pack2bf(o0, o1);
}

// ---------------- SpMM F=64: 2 edges/wave; out = relu(...) bf16 ----------------

__launch_bounds__(256)
__global__ void spmm64_kernel(const float* __restrict__ packed,
                              const int* __restrict__ rp, const unsigned short* __restrict__ X,
                              const float* __restrict__ AM, const float* __restrict__ bias,
                              unsigned short* __restrict__ out, int n) {
    const int lane = threadIdx.x & 63;
    const int g = lane >> 5;
    const int ls = lane & 31;
    const int r = (int)((blockIdx.x * (unsigned)blockDim.x + threadIdx.x) >> 6);
    if (r >= n) return;
    const int s = __builtin_amdgcn_readfirstlane(rp[r]);
    const int e = __builtin_amdgcn_readfirstlane(rp[r + 1]);

    float acc0 = 0.0f, acc1 = 0.0f;
    for (int base = s; base < e; base += 64) {
        const int nn = min(64, e - base);
        int ci = 0; float vf = 0.0f;
        if (lane < nn) {
            const float3 pk = *(const float3*)&packed[(size_t)3 * (base + lane)];
            ci = __builtin_bit_cast(int, pk.x);
            vf = pk.y;
        }
        for (int j = 0; j < nn; j += 8) {
#pragma unroll
            for (int q = 0; q < 4; ++q) {
                const int jj = j + 2 * q + g;
                const bool ok = jj < nn;
                const int idx = jj & 63;
                const int c = __shfl(ci, idx);
                const float v = __shfl(vf, idx);
                if (ok) {
                    const unsigned u = *(const unsigned*)(X + (size_t)c * 64 + ls * 2);
                    acc0 += v * bf_lo(u);
                    acc1 += v * bf_hi(u);
                }
            }
        }
    }
    acc0 += __shfl_xor(acc0, 32);
    acc1 += __shfl_xor(acc1, 32);

    if (lane < 32) {
        const float am = AM[r];
        const float o0 = fminf(fmaxf(acc0 * am + bias[2 * ls], 0.0f), 1e30f);
        const float o1 = fminf(fmaxf(acc1 * am + bias[2 * ls + 1], 0.0f), 1e30f);
        ((unsigned*)out)[(size_t)r * 32 + ls] = pack2bf(o0, o1);
    }
}

// ---------------- SpMM F=40 + log_softmax: 3 edges/wave ----------------

__launch_bounds__(256)
__global__ void spmm40_kernel(const float* __restrict__ packed,
                              const int* __restrict__ rp, const unsigned short* __restrict__ X,
                              const float* __restrict__ bias,
                              float* __restrict__ out, int n) {
    const int lane = threadIdx.x & 63;
    const int g = lane / 20;
    const int ls = lane - 20 * g;
    const bool active = g < 3;
    const int r = (int)((blockIdx.x * (unsigned)blockDim.x + threadIdx.x) >> 6);
    if (r >= n) return;
    const int s = __builtin_amdgcn_readfirstlane(rp[r]);
    const int e = __builtin_amdgcn_readfirstlane(rp[r + 1]);

    float acc0 = 0.0f, acc1 = 0.0f;
    for (int base = s; base < e; base += 64) {
        const int nn = min(64, e - base);
        int ci = 0; float vf = 0.0f;
        if (lane < nn) {
            const float3 pk = *(const float3*)&packed[(size_t)3 * (base + lane)];
            ci = __builtin_bit_cast(int, pk.x);
            vf = pk.z;                   // adj (not adjZ) values
        }
        for (int j = 0; j < nn; j += 12) {
#pragma unroll
            for (int q = 0; q < 4; ++q) {
                const int jj = j + 3 * q + g;
                const bool ok = active && jj < nn;
                const int idx = jj & 63;
                const int c = __shfl(ci, idx);
                const float v = __shfl(vf, idx);
                if (ok) {
                    const unsigned u = *(const unsigned*)(X + (size_t)c * 40 + ls * 2);
                    acc0 += v * bf_lo(u);
                    acc1 += v * bf_hi(u);
                }
            }
        }
    }
    {
        const float a1 = __shfl(acc0, (lane + 20) & 63);
        const float a2 = __shfl(acc0, (lane + 40) & 63);
        const float b1 = __shfl(acc1, (lane + 20) & 63);
        const float b2 = __shfl(acc1, (lane + 40) & 63);
        acc0 += a1 + a2;
        acc1 += b1 + b2;
    }

    const bool own = lane < 20;
    const float vv0 = own ? fminf(fmaxf(acc0 + bias[2 * ls], -1e30f), 1e30f) : -INFINITY;
    const float vv1 = own ? fminf(fmaxf(acc1 + bias[2 * ls + 1], -1e30f), 1e30f) : -INFINITY;
    float mx = fmaxf(vv0, vv1);
#pragma unroll
    for (int off = 32; off > 0; off >>= 1) mx = fmaxf(mx, __shfl_xor(mx, off));
    float sum = own ? (expf(vv0 - mx) + expf(vv1 - mx)) : 0.0f;
#pragma unroll
    for (int off = 32; off > 0; off >>= 1) sum += __shfl_xor(sum, off);
    if (own) {
        const float lse = mx + logf(sum);
        *(float2*)(out + (size_t)r * 40 + ls * 2) = make_float2(vv0 - lse, vv1 - lse);
    }
}

// ---------------- launch ----------------

extern "C" void kernel_launch(void* const* d_in, const int* in_sizes, int n_in,
                              void* d_out, int out_size, void* d_ws, size_t ws_size,
                              hipStream_t stream) {
    const float* x    = (const float*)d_in[0];
    const float* M    = (const float*)d_in[1];
    const float* AM   = (const float*)d_in[2];
    const float* adjv = (const float*)d_in[3];
    const float* adjZ = (const float*)d_in[4];
    const float* W0   = (const float*)d_in[5];
    const float* b0   = (const float*)d_in[6];
    const float* W1   = (const float*)d_in[7];
    const float* b1   = (const float*)d_in[8];
    const float* W2   = (const float*)d_in[9];
    const float* b2   = (const float*)d_in[10];
    const int* row    = (const int*)d_in[11];
    const int* col    = (const int*)d_in[12];
    float* out = (float*)d_out;

    const int n = in_sizes[1];   // N
    const int E = in_sizes[3];   // edges

    // workspace layout (~61.2 MB, unchanged footprint):
    // t_f region (N*128 floats = 25.6MB): t_buf bf16 (12.8MB) + wt arrays +
    // cnt8 (1.6MB) in the otherwise-unused upper half.
    float* t_f   = (float*)d_ws;
    unsigned short* t_buf = (unsigned short*)t_f;           // N*128 bf16 gather target
    unsigned short* wt0 = t_buf + (size_t)n * 128;          // 128*128
    unsigned short* wt1 = wt0 + 128 * 128;                  // 64*128
    unsigned short* wt2 = wt1 + 64 * 128;                   // 48*64
    int* cnt8    = (int*)(wt2 + 48 * 64 + 32);              // 8*N ints (4B-aligned region)
    float* h_f   = t_f + (size_t)n * 128;                   // N*128 floats reserved
    unsigned short* h_buf = (unsigned short*)h_f;           // bf16 h0 / h1
    int* cnt     = (int*)(h_f + (size_t)n * 128);           // N (row totals)
    int* rp      = cnt + n;                                 // N+1
    int* bsums   = rp + (n + 1);                            // 64
    float* packed = (float*)(bsums + 64);                   // E*3 floats
    int* pos_local = (int*)h_f;                             // E ints (aliased, dead before spmm128)

    hipMemsetAsync(cnt8, 0, (size_t)8 * n * sizeof(int), stream);
    prep_wt<<<(128 * 128 + 64 * 128 + 48 * 64 + 255) / 256, 256, 0, stream>>>(
        W0, W1, W2, wt0, wt1, wt2);

    const int gemm0Blocks = (n + 63) / 64;
    const int histBlocks  = (E + 255) / 256;
    gemm0_hist<<<gemm0Blocks + histBlocks, 256, 0, stream>>>(x, M, wt0, t_buf, row, cnt8,
                                                             pos_local, n, E, gemm0Blocks);

    combine8<<<(n + 255) / 256, 256, 0, stream>>>(cnt8, cnt, n);
    const int nblk = (n + 1023) >> 10;  // <=64 required by scan_top
    scan_part<<<nblk, 256, 0, stream>>>(cnt, rp, bsums, n);
    scan_top<<<1, 64, 0, stream>>>(bsums, nblk);
    scan_add8<<<(n + 255) / 256, 256, 0, stream>>>(rp, bsums, cnt8, n, E);
    scatter_kernel<<<(E + 255) / 256, 256, 0, stream>>>(row, col, adjv, adjZ, cnt8,
                                                        pos_local, packed, E, n, gemm0Blocks);

    const int spmmBlocks = (n + 3) / 4;   // 4 rows (waves) per block
    const int gemmBlocks = (n + 63) / 64;

    // layer 0 aggregate: h_buf = M⊙relu(AM⊙agg+b0) bf16  (overwrites pos_local alias)
    spmm128_kernel<<<spmmBlocks, 256, 0, stream>>>(packed, rp, t_buf, AM, M, b0, h_buf, n);
    // layer 1: t_buf = h_buf@W1 bf16 (M already folded)
    gemm_mfma<128, 64, 64, true, false><<<gemmBlocks, 256, 0, stream>>>(h_buf, nullptr, wt1,
                                                                        t_buf, n);
    spmm64_kernel<<<spmmBlocks, 256, 0, stream>>>(packed, rp, t_buf, AM, b1, h_buf, n);
    // layer 2: t_buf = h1@W2 bf16 (stride 40)
    gemm_mfma<64, 40, 48, true, false><<<gemmBlocks, 256, 0, stream>>>(h_buf, nullptr, wt2,
                                                                       t_buf, n);
    spmm40_kernel<<<spmmBlocks, 256, 0, stream>>>(packed, rp, t_buf, b2, out, n);
}